// Round 2
// baseline (820.359 us; speedup 1.0000x reference)
//
#include <hip/hip_runtime.h>

// ---------------- problem constants ----------------
#define B_    2
#define S_    2048
#define HID_  3584
#define H_    16
#define KV_   8
#define D_    256
#define RQ_   6
#define NPROJ 2688
#define HD_   4096
#define MTOK  4096
#define EPS_  1e-6f
#define NEG_  -2.3819763e38f
#define SCALE_ 0.0625f   // 256^-0.5

typedef unsigned short u16;
typedef __attribute__((ext_vector_type(8))) short short8;
typedef __attribute__((ext_vector_type(4))) float f32x4;

__device__ __forceinline__ u16 f2bf(float f) {
  unsigned u = __float_as_uint(f);
  u += 0x7fffu + ((u >> 16) & 1u);
  return (u16)(u >> 16);
}

__device__ __forceinline__ void gl_lds16(const void* g, void* l) {
  __builtin_amdgcn_global_load_lds((__attribute__((address_space(1))) void*)g,
                                   (__attribute__((address_space(3))) void*)l, 16, 0, 0);
}

// ---------------- elementwise f32 -> bf16 ----------------
__global__ __launch_bounds__(256) void cvt_f32_bf16(const float* __restrict__ src,
                                                    u16* __restrict__ dst, int n) {
  int i = blockIdx.x * 256 + threadIdx.x;
  const int stride = gridDim.x * 256;
  const int n4 = n >> 2;
  for (; i < n4; i += stride) {
    float4 v = ((const float4*)src)[i];
    ushort4 o;
    o.x = f2bf(v.x); o.y = f2bf(v.y); o.z = f2bf(v.z); o.w = f2bf(v.w);
    ((ushort4*)dst)[i] = o;
  }
}

// ---------------- tiled transpose f32(RxC) -> bf16(CxR) ----------------
__global__ __launch_bounds__(256) void transpose_f32_bf16(const float* __restrict__ src,
                                                          u16* __restrict__ dst, int R, int C) {
  __shared__ float tile[32][33];
  const int tx = threadIdx.x & 31, ty = threadIdx.x >> 5;
  const int r0 = blockIdx.x << 5, c0 = blockIdx.y << 5;
#pragma unroll
  for (int j = 0; j < 4; ++j) {
    int r = r0 + ty + j * 8, c = c0 + tx;
    tile[ty + j * 8][tx] = (r < R && c < C) ? src[(size_t)r * C + c] : 0.f;
  }
  __syncthreads();
#pragma unroll
  for (int j = 0; j < 4; ++j) {
    int cc = c0 + ty + j * 8, rr = r0 + tx;
    if (cc < C && rr < R) dst[(size_t)cc * R + rr] = f2bf(tile[tx][ty + j * 8]);
  }
}

// ---------------- tiled transpose bf16(RxC)->bf16(CxR), batched z ----------------
__global__ __launch_bounds__(256) void transpose_bf16_b(const u16* __restrict__ src,
                                                        u16* __restrict__ dst, int R, int C) {
  __shared__ u16 tile[32][34];
  const size_t plane = (size_t)R * C;
  const u16* s = src + (size_t)blockIdx.z * plane;
  u16* d = dst + (size_t)blockIdx.z * plane;
  const int tx = threadIdx.x & 31, ty = threadIdx.x >> 5;
  const int r0 = blockIdx.x << 5, c0 = blockIdx.y << 5;
#pragma unroll
  for (int j = 0; j < 4; ++j) {
    int r = r0 + ty + j * 8, c = c0 + tx;
    tile[ty + j * 8][tx] = (r < R && c < C) ? s[(size_t)r * C + c] : (u16)0;
  }
  __syncthreads();
#pragma unroll
  for (int j = 0; j < 4; ++j) {
    int cc = c0 + ty + j * 8, rr = r0 + tx;
    if (cc < C && rr < R) d[(size_t)cc * R + rr] = tile[tx][ty + j * 8];
  }
}

// ---------------- m97-style 128x128 GEMM, A(MxK) row-major, Bm(NxK) row-major (B^T) ----
__global__ __launch_bounds__(256, 2)
void gemm_bt(const u16* __restrict__ A, const u16* __restrict__ Bm, float* __restrict__ C,
             int M, int N, int K, int lda, int ldb, int ldc) {
  __shared__ __align__(16) u16 As[2][4096];
  __shared__ __align__(16) u16 Bs[2][4096];
  const int t = threadIdx.x;
  const int lane = t & 63;
  const int lq = lane & 15, lg = lane >> 4;
  const int wid = t >> 6;
  const int wr = wid >> 1, wc = wid & 1;
  const int m0 = blockIdx.x * 128, n0 = blockIdx.y * 128;

  const int row0 = t >> 2;
  const int row1 = 64 + row0;
  const int sl = t & 3;
  const char* ga0 = (const char*)(A + (size_t)(m0 + row0) * lda) + ((sl ^ ((row0 >> 1) & 3)) << 4);
  const char* ga1 = (const char*)(A + (size_t)(m0 + row1) * lda) + ((sl ^ ((row1 >> 1) & 3)) << 4);
  const char* gb0 = (const char*)(Bm + (size_t)(n0 + row0) * ldb) + ((sl ^ ((row0 >> 1) & 3)) << 4);
  const char* gb1 = (const char*)(Bm + (size_t)(n0 + row1) * ldb) + ((sl ^ ((row1 >> 1) & 3)) << 4);
  u16* Abase = &As[0][0];
  u16* Bbase = &Bs[0][0];
  const int ldst0 = t * 8, ldst1 = 2048 + t * 8;

  int aoff[4], boff[4];
#pragma unroll
  for (int i = 0; i < 4; ++i) {
    int ra = wr * 64 + i * 16 + lq;
    aoff[i] = ra * 32 + ((lg ^ ((ra >> 1) & 3)) << 3);
    int rb = wc * 64 + i * 16 + lq;
    boff[i] = rb * 32 + ((lg ^ ((rb >> 1) & 3)) << 3);
  }

  f32x4 zero = {0.f, 0.f, 0.f, 0.f};
  f32x4 acc[4][4];
#pragma unroll
  for (int i = 0; i < 4; ++i)
#pragma unroll
    for (int j = 0; j < 4; ++j) acc[i][j] = zero;

  const int nk = K >> 5;
  gl_lds16(ga0, Abase + ldst0);
  gl_lds16(ga1, Abase + ldst1);
  gl_lds16(gb0, Bbase + ldst0);
  gl_lds16(gb1, Bbase + ldst1);
  __syncthreads();
  int cur = 0;
  for (int kt = 0; kt < nk; ++kt) {
    if (kt + 1 < nk) {
      const size_t ko = (size_t)(kt + 1) * 64;
      const int nb = (cur ^ 1) * 4096;
      gl_lds16(ga0 + ko, Abase + nb + ldst0);
      gl_lds16(ga1 + ko, Abase + nb + ldst1);
      gl_lds16(gb0 + ko, Bbase + nb + ldst0);
      gl_lds16(gb1 + ko, Bbase + nb + ldst1);
    }
    const int cb = cur * 4096;
    short8 af[4], bfr[4];
#pragma unroll
    for (int i = 0; i < 4; ++i) {
      af[i] = *(const short8*)(Abase + cb + aoff[i]);
      bfr[i] = *(const short8*)(Bbase + cb + boff[i]);
    }
#pragma unroll
    for (int i = 0; i < 4; ++i)
#pragma unroll
      for (int j = 0; j < 4; ++j)
        acc[i][j] = __builtin_amdgcn_mfma_f32_16x16x32_bf16(af[i], bfr[j], acc[i][j], 0, 0, 0);
    __syncthreads();
    cur ^= 1;
  }
#pragma unroll
  for (int i = 0; i < 4; ++i)
#pragma unroll
    for (int j = 0; j < 4; ++j) {
      const int row = m0 + wr * 64 + i * 16 + lg * 4;
      const int col = n0 + wc * 64 + j * 16 + lq;
      float* cp = C + (size_t)row * ldc + col;
#pragma unroll
      for (int r = 0; r < 4; ++r) cp[(size_t)r * ldc] = acc[i][j][r];
    }
}

// ---------------- per-token RMSNorm + RoPE + rank contraction -> Q,K,V (bf16) ------
__global__ __launch_bounds__(256)
void build_qkv(const float* __restrict__ P, const float* __restrict__ freqs,
               const float* __restrict__ qw, const float* __restrict__ kw,
               u16* __restrict__ Qg, u16* __restrict__ Kg, u16* __restrict__ Vg) {
  const int token = blockIdx.x;
  const int b = token >> 11, s = token & 2047;
  const int d = threadIdx.x;
  const float* row = P + (size_t)token * NPROJ;
  __shared__ float aL[128];
  __shared__ float rQ[6][256];
  __shared__ float rK[2][256];
  __shared__ float red[4][8];

  if (d < 128) aL[d] = row[d];
  float bq[6], bk[2], bv[2];
#pragma unroll
  for (int r = 0; r < 6; ++r) bq[r] = row[128 + r * 256 + d];
#pragma unroll
  for (int r = 0; r < 2; ++r) bk[r] = row[1664 + r * 256 + d];
#pragma unroll
  for (int r = 0; r < 2; ++r) bv[r] = row[2176 + r * 256 + d];

  float sq[8];
#pragma unroll
  for (int r = 0; r < 6; ++r) sq[r] = bq[r] * bq[r];
  sq[6] = bk[0] * bk[0];
  sq[7] = bk[1] * bk[1];
#pragma unroll
  for (int j = 0; j < 8; ++j) {
    sq[j] += __shfl_xor(sq[j], 32, 64);
    sq[j] += __shfl_xor(sq[j], 16, 64);
    sq[j] += __shfl_xor(sq[j], 8, 64);
    sq[j] += __shfl_xor(sq[j], 4, 64);
    sq[j] += __shfl_xor(sq[j], 2, 64);
    sq[j] += __shfl_xor(sq[j], 1, 64);
  }
  const int lane = d & 63, wv = d >> 6;
  if (lane == 0) {
#pragma unroll
    for (int j = 0; j < 8; ++j) red[wv][j] = sq[j];
  }
  __syncthreads();
  float inv[8];
#pragma unroll
  for (int j = 0; j < 8; ++j) {
    float ss = red[0][j] + red[1][j] + red[2][j] + red[3][j];
    inv[j] = rsqrtf(ss * (1.0f / 256.0f) + EPS_);
  }
  const float gq = 1.f + qw[d], gk = 1.f + kw[d];
#pragma unroll
  for (int r = 0; r < 6; ++r) rQ[r][d] = bq[r] * inv[r] * gq;
#pragma unroll
  for (int r = 0; r < 2; ++r) rK[r][d] = bk[r] * inv[6 + r] * gk;
  __syncthreads();

  const int dh = d & 127;
  const float co = freqs[(s * 128 + dh) * 2 + 0];
  const float sn = freqs[(s * 128 + dh) * 2 + 1];
  float q_ro[6], k_ro[2];
  if (d < 128) {
#pragma unroll
    for (int r = 0; r < 6; ++r) q_ro[r] = rQ[r][d] * co - rQ[r][d + 128] * sn;
#pragma unroll
    for (int r = 0; r < 2; ++r) k_ro[r] = rK[r][d] * co - rK[r][d + 128] * sn;
  } else {
#pragma unroll
    for (int r = 0; r < 6; ++r) q_ro[r] = rQ[r][d] * co + rQ[r][d - 128] * sn;
#pragma unroll
    for (int r = 0; r < 2; ++r) k_ro[r] = rK[r][d] * co + rK[r][d - 128] * sn;
  }
  const float qs = SCALE_ * (1.0f / 6.0f);
#pragma unroll
  for (int h = 0; h < 16; ++h) {
    float a = 0.f;
#pragma unroll
    for (int r = 0; r < 6; ++r) a += aL[h * 6 + r] * q_ro[r];
    Qg[((size_t)(b * H_ + h) * S_ + s) * D_ + d] = f2bf(a * qs);
  }
#pragma unroll
  for (int kv = 0; kv < 8; ++kv) {
    float ak = aL[96 + kv * 2] * k_ro[0] + aL[96 + kv * 2 + 1] * k_ro[1];
    Kg[((size_t)(b * KV_ + kv) * S_ + s) * D_ + d] = f2bf(ak * 0.5f);
    float av = aL[112 + kv * 2] * bv[0] + aL[112 + kv * 2 + 1] * bv[1];
    Vg[((size_t)(b * KV_ + kv) * S_ + s) * D_ + d] = f2bf(av * 0.5f);
  }
}

// ---------------- flash attention v2: 512 thr, 2 GQA heads/block, KVB=32, D=256 ----
// 8 waves = 2 heads x 4 q16-blocks. K,V double-buffered; 1 barrier/tile; LPT grid.
__global__ __launch_bounds__(512, 4)
void attn_kernel(const u16* __restrict__ Qg, const u16* __restrict__ Kg,
                 const u16* __restrict__ VTg, u16* __restrict__ Og) {
  __shared__ __align__(16) u16 Kbuf[2][8192];   // 32 kv x 256 d, slot^(r&7)
  __shared__ __align__(16) u16 Vbuf[2][8192];   // 256 d x 32 kv, slot^((d>>1)&3)
  __shared__ __align__(16) u16 Pbuf[8][512];    // per-wave 16q x 32kv, bit-swapped rows

  const int t = threadIdx.x;
  const int lane = t & 63;
  const int lq = lane & 15, lg = lane >> 4;
  const int wid = t >> 6;
  const int qt = 31 - blockIdx.x;               // LPT: big tiles first
  const int kvh = blockIdx.y, b = blockIdx.z;
  const int h = kvh * 2 + (wid & 1);
  const int qw = wid >> 1;
  const int q0 = qt * 64;

  const u16* Kplane = Kg + (size_t)(b * KV_ + kvh) * S_ * D_;
  const u16* VTplane = VTg + (size_t)(b * KV_ + kvh) * D_ * S_;

  // Q fragments in registers
  const int qrow = q0 + qw * 16 + lq;
  const u16* Qrow = Qg + ((size_t)(b * H_ + h) * S_ + qrow) * D_;
  short8 qf[8];
#pragma unroll
  for (int ks = 0; ks < 8; ++ks) qf[ks] = *(const short8*)(Qrow + ks * 32 + lg * 8);

  // staging offsets (512 threads: 2 issues per buffer)
  const int ksrc0 = (t >> 5) * 256 + (((t & 31) ^ ((t >> 5) & 7)) << 3);        // +4096 for issue 1
  const int vsrc0 = (t >> 2) * S_ + (((t & 3) ^ ((t >> 3) & 3)) << 3);          // +128*S_ for issue 1
  const int voffb = lq * 32 + ((lg ^ ((lq >> 1) & 3)) << 3);                    // V frag read base

  auto stageK = [&](int tile, u16* dst) {
    const u16* kp = Kplane + (size_t)tile * 32 * D_;
    gl_lds16(kp + ksrc0, dst + t * 8);
    gl_lds16(kp + ksrc0 + 4096, dst + 4096 + t * 8);
  };
  auto stageV = [&](int tile, u16* dst) {
    const u16* vp = VTplane + tile * 32;
    gl_lds16(vp + vsrc0, dst + t * 8);
    gl_lds16(vp + vsrc0 + 128 * S_, dst + 4096 + t * 8);
  };

  f32x4 zero = {0.f, 0.f, 0.f, 0.f};
  f32x4 oacc[16];
#pragma unroll
  for (int db = 0; db < 16; ++db) oacc[db] = zero;
  float m_r[4], l_r[4];
#pragma unroll
  for (int r = 0; r < 4; ++r) { m_r[r] = NEG_; l_r[r] = 0.f; }

  const int qro = q0 + qw * 16 + lg * 4;   // C-layout q rows
  const int nt = 2 * (qt + 1);

  stageK(0, &Kbuf[0][0]);
  stageV(0, &Vbuf[0][0]);
  __syncthreads();
  int cur = 0;
  for (int it = 0; it < nt; ++it) {
    const int kv0 = it * 32;
    // ---- QK^T from Kbuf[cur]
    const u16* Kb = &Kbuf[cur][0];
    f32x4 sacc[2];
    sacc[0] = zero; sacc[1] = zero;
    __builtin_amdgcn_s_setprio(1);
#pragma unroll
    for (int kb = 0; kb < 2; ++kb) {
      const int rbase = (kb * 16 + lq) * 256;
      const int sw = lq & 7;
#pragma unroll
      for (int ks = 0; ks < 8; ++ks) {
        short8 kf = *(const short8*)(Kb + rbase + (((ks * 4 + lg) ^ sw) << 3));
        sacc[kb] = __builtin_amdgcn_mfma_f32_16x16x32_bf16(qf[ks], kf, sacc[kb], 0, 0, 0);
      }
    }
    __builtin_amdgcn_s_setprio(0);
    // ---- softcap + causal mask (tail tiles only)
    const bool tail = (it >= 2 * qt);
#pragma unroll
    for (int kb = 0; kb < 2; ++kb)
#pragma unroll
      for (int r = 0; r < 4; ++r) {
        float x = sacc[kb][r];
        const float e = __expf(-fabsf(x) * 0.04f);
        const float th = (1.f - e) * __builtin_amdgcn_rcpf(1.f + e);
        x = copysignf(50.0f * th, x);
        if (tail && (kv0 + kb * 16 + lq > qro + r)) x = NEG_;
        sacc[kb][r] = x;
      }
    // ---- row max (16-lane groups share a row)
    float vmax[4];
#pragma unroll
    for (int r = 0; r < 4; ++r) {
      float v = fmaxf(sacc[0][r], sacc[1][r]);
      v = fmaxf(v, __shfl_xor(v, 1, 16));
      v = fmaxf(v, __shfl_xor(v, 2, 16));
      v = fmaxf(v, __shfl_xor(v, 4, 16));
      v = fmaxf(v, __shfl_xor(v, 8, 16));
      vmax[r] = v;
    }
    // ---- T13 defer-max: only rescale when max grew past m+8
    const bool grow = (vmax[0] > m_r[0] + 8.f) | (vmax[1] > m_r[1] + 8.f) |
                      (vmax[2] > m_r[2] + 8.f) | (vmax[3] > m_r[3] + 8.f);
    if (__any(grow)) {
      float c_r[4];
#pragma unroll
      for (int r = 0; r < 4; ++r) {
        const float mn = fmaxf(m_r[r], vmax[r]);
        c_r[r] = __expf(m_r[r] - mn);
        m_r[r] = mn;
        l_r[r] *= c_r[r];
      }
#pragma unroll
      for (int db = 0; db < 16; ++db) {
        oacc[db][0] *= c_r[0]; oacc[db][1] *= c_r[1];
        oacc[db][2] *= c_r[2]; oacc[db][3] *= c_r[3];
      }
    }
    // ---- exp + row sums (masked -> exp(NEG-m)=0 naturally)
#pragma unroll
    for (int r = 0; r < 4; ++r) {
      const float p0 = __expf(sacc[0][r] - m_r[r]);
      const float p1 = __expf(sacc[1][r] - m_r[r]);
      sacc[0][r] = p0; sacc[1][r] = p1;
      float ps = p0 + p1;
      ps += __shfl_xor(ps, 1, 16);
      ps += __shfl_xor(ps, 2, 16);
      ps += __shfl_xor(ps, 4, 16);
      ps += __shfl_xor(ps, 8, 16);
      l_r[r] += ps;
    }
    // ---- prefetch next tile into the other buffers (drained by tile-end barrier)
    if (it + 1 < nt) {
      stageK(it + 1, &Kbuf[cur ^ 1][0]);
      stageV(it + 1, &Vbuf[cur ^ 1][0]);
    }
    // ---- P -> LDS (bank-conflict-free layout), PV from Vbuf[cur]
    u16* Pw = &Pbuf[wid][0];
#pragma unroll
    for (int kb = 0; kb < 2; ++kb)
#pragma unroll
      for (int r = 0; r < 4; ++r) {
        const int rowp = r * 4 + lg;                       // bit-swapped row
        const int s = (kb * 2 + (lq >> 3)) ^ lg;           // 16B-slot XOR
        Pw[rowp * 32 + s * 8 + (lq & 7)] = f2bf(sacc[kb][r]);
      }
    const int rpp = ((lq & 3) << 2) | (lq >> 2);
    short8 pf = *(const short8*)(Pw + rpp * 32 + ((lg ^ (lq >> 2)) << 3));
    const u16* Vb = &Vbuf[cur][0];
    __builtin_amdgcn_s_setprio(1);
#pragma unroll
    for (int db = 0; db < 16; ++db) {
      short8 vf = *(const short8*)(Vb + db * 512 + voffb);
      oacc[db] = __builtin_amdgcn_mfma_f32_16x16x32_bf16(pf, vf, oacc[db], 0, 0, 0);
    }
    __builtin_amdgcn_s_setprio(0);
    __syncthreads();
    cur ^= 1;
  }
  // ---- epilogue
#pragma unroll
  for (int r = 0; r < 4; ++r) {
    const float inv = __builtin_amdgcn_rcpf(l_r[r]);
    u16* orow = Og + (size_t)(b * S_ + qro + r) * HD_ + h * D_;
#pragma unroll
    for (int db = 0; db < 16; ++db) orow[db * 16 + lq] = f2bf(oacc[db][r] * inv);
  }
}

// ---------------- launcher ----------------
extern "C" void kernel_launch(void* const* d_in, const int* in_sizes, int n_in,
                              void* d_out, int out_size, void* d_ws, size_t ws_size,
                              hipStream_t stream) {
  const float* hs    = (const float*)d_in[0];
  const float* freqs = (const float*)d_in[1];
  const float* W_A_q = (const float*)d_in[8];
  const float* W_A_k = (const float*)d_in[9];
  const float* W_A_v = (const float*)d_in[10];
  const float* W_B_q = (const float*)d_in[11];
  const float* W_B_k = (const float*)d_in[12];
  const float* W_B_v = (const float*)d_in[13];
  const float* Wo    = (const float*)d_in[14];
  const float* qw    = (const float*)d_in[15];
  const float* kw    = (const float*)d_in[16];
  float* out = (float*)d_out;

  char* ws = (char*)d_ws;
  u16* hsb = (u16*)(ws);                    // 4096x3584 bf16
  u16* WT  = (u16*)(ws + 29360128);         // 2688x3584 bf16
  u16* WoT = (u16*)(ws + 48627712);         // 3584x4096 bf16
  u16* Qg  = (u16*)(ws + 77987840);         // (B,H,S,D) bf16
  u16* Kg  = (u16*)(ws + 111542272);        // (B,KV,S,D) bf16
  u16* Vg  = (u16*)(ws + 128319488);        // (B,KV,S,D) bf16
  u16* VTg = (u16*)(ws + 145096704);        // (B,KV,D,S) bf16
  u16* AOg = (u16*)(ws + 161873920);        // (B*S, H*D) bf16
  float* Pout = (float*)d_out;              // 4096x2688 f32 scratch inside d_out

  cvt_f32_bf16<<<1024, 256, 0, stream>>>(hs, hsb, MTOK * HID_);
  transpose_f32_bf16<<<dim3(112, 3),   256, 0, stream>>>(W_A_q, WT + (size_t)0 * HID_,    HID_, 96);
  transpose_f32_bf16<<<dim3(112, 1),   256, 0, stream>>>(W_A_k, WT + (size_t)96 * HID_,   HID_, 16);
  transpose_f32_bf16<<<dim3(112, 1),   256, 0, stream>>>(W_A_v, WT + (size_t)112 * HID_,  HID_, 16);
  transpose_f32_bf16<<<dim3(112, 48),  256, 0, stream>>>(W_B_q, WT + (size_t)128 * HID_,  HID_, 1536);
  transpose_f32_bf16<<<dim3(112, 16),  256, 0, stream>>>(W_B_k, WT + (size_t)1664 * HID_, HID_, 512);
  transpose_f32_bf16<<<dim3(112, 16),  256, 0, stream>>>(W_B_v, WT + (size_t)2176 * HID_, HID_, 512);
  transpose_f32_bf16<<<dim3(128, 112), 256, 0, stream>>>(Wo, WoT, HD_, HID_);

  gemm_bt<<<dim3(32, 21), 256, 0, stream>>>(hsb, WT, Pout, MTOK, NPROJ, HID_, HID_, HID_, NPROJ);
  build_qkv<<<4096, 256, 0, stream>>>(Pout, freqs, qw, kw, Qg, Kg, Vg);
  transpose_bf16_b<<<dim3(64, 8, 16), 256, 0, stream>>>(Vg, VTg, S_, D_);
  attn_kernel<<<dim3(32, 8, 2), 512, 0, stream>>>(Qg, Kg, VTg, AOg);
  gemm_bt<<<dim3(32, 28), 256, 0, stream>>>(AOg, WoT, out, MTOK, HID_, HD_, HD_, HD_, HID_);
}

// Round 3
// 469.997 us; speedup vs baseline: 1.7455x; 1.7455x over previous
//
#include <hip/hip_runtime.h>

// ---------------- problem constants ----------------
#define B_    2
#define S_    2048
#define HID_  3584
#define H_    16
#define KV_   8
#define D_    256
#define RQ_   6
#define NPROJ 2688
#define HD_   4096
#define MTOK  4096
#define EPS_  1e-6f
#define NEG_  -2.3819763e38f
#define SCALE_ 0.0625f   // 256^-0.5

typedef unsigned short u16;
typedef __attribute__((ext_vector_type(8))) short short8;
typedef __attribute__((ext_vector_type(4))) float f32x4;

__device__ __forceinline__ u16 f2bf(float f) {
  unsigned u = __float_as_uint(f);
  u += 0x7fffu + ((u >> 16) & 1u);
  return (u16)(u >> 16);
}

__device__ __forceinline__ void gl_lds16(const void* g, void* l) {
  __builtin_amdgcn_global_load_lds((__attribute__((address_space(1))) void*)g,
                                   (__attribute__((address_space(3))) void*)l, 16, 0, 0);
}

// ---------------- elementwise f32 -> bf16 ----------------
__global__ __launch_bounds__(256) void cvt_f32_bf16(const float* __restrict__ src,
                                                    u16* __restrict__ dst, int n) {
  int i = blockIdx.x * 256 + threadIdx.x;
  const int stride = gridDim.x * 256;
  const int n4 = n >> 2;
  for (; i < n4; i += stride) {
    float4 v = ((const float4*)src)[i];
    ushort4 o;
    o.x = f2bf(v.x); o.y = f2bf(v.y); o.z = f2bf(v.z); o.w = f2bf(v.w);
    ((ushort4*)dst)[i] = o;
  }
}

// ---------------- tiled transpose f32(RxC) -> bf16(CxR) ----------------
__global__ __launch_bounds__(256) void transpose_f32_bf16(const float* __restrict__ src,
                                                          u16* __restrict__ dst, int R, int C) {
  __shared__ float tile[32][33];
  const int tx = threadIdx.x & 31, ty = threadIdx.x >> 5;
  const int r0 = blockIdx.x << 5, c0 = blockIdx.y << 5;
#pragma unroll
  for (int j = 0; j < 4; ++j) {
    int r = r0 + ty + j * 8, c = c0 + tx;
    tile[ty + j * 8][tx] = (r < R && c < C) ? src[(size_t)r * C + c] : 0.f;
  }
  __syncthreads();
#pragma unroll
  for (int j = 0; j < 4; ++j) {
    int cc = c0 + ty + j * 8, rr = r0 + tx;
    if (cc < C && rr < R) dst[(size_t)cc * R + rr] = f2bf(tile[tx][ty + j * 8]);
  }
}

// ---------------- tiled transpose bf16(RxC)->bf16(CxR), batched z ----------------
__global__ __launch_bounds__(256) void transpose_bf16_b(const u16* __restrict__ src,
                                                        u16* __restrict__ dst, int R, int C) {
  __shared__ u16 tile[32][34];
  const size_t plane = (size_t)R * C;
  const u16* s = src + (size_t)blockIdx.z * plane;
  u16* d = dst + (size_t)blockIdx.z * plane;
  const int tx = threadIdx.x & 31, ty = threadIdx.x >> 5;
  const int r0 = blockIdx.x << 5, c0 = blockIdx.y << 5;
#pragma unroll
  for (int j = 0; j < 4; ++j) {
    int r = r0 + ty + j * 8, c = c0 + tx;
    tile[ty + j * 8][tx] = (r < R && c < C) ? s[(size_t)r * C + c] : (u16)0;
  }
  __syncthreads();
#pragma unroll
  for (int j = 0; j < 4; ++j) {
    int cc = c0 + ty + j * 8, rr = r0 + tx;
    if (cc < C && rr < R) d[(size_t)cc * R + rr] = tile[tx][ty + j * 8];
  }
}

// ---------------- m97-style 128x128 GEMM, A(MxK) row-major, Bm(NxK) row-major (B^T) ----
__global__ __launch_bounds__(256, 2)
void gemm_bt(const u16* __restrict__ A, const u16* __restrict__ Bm, float* __restrict__ C,
             int M, int N, int K, int lda, int ldb, int ldc) {
  __shared__ __align__(16) u16 As[2][4096];
  __shared__ __align__(16) u16 Bs[2][4096];
  const int t = threadIdx.x;
  const int lane = t & 63;
  const int lq = lane & 15, lg = lane >> 4;
  const int wid = t >> 6;
  const int wr = wid >> 1, wc = wid & 1;
  const int m0 = blockIdx.x * 128, n0 = blockIdx.y * 128;

  const int row0 = t >> 2;
  const int row1 = 64 + row0;
  const int sl = t & 3;
  const char* ga0 = (const char*)(A + (size_t)(m0 + row0) * lda) + ((sl ^ ((row0 >> 1) & 3)) << 4);
  const char* ga1 = (const char*)(A + (size_t)(m0 + row1) * lda) + ((sl ^ ((row1 >> 1) & 3)) << 4);
  const char* gb0 = (const char*)(Bm + (size_t)(n0 + row0) * ldb) + ((sl ^ ((row0 >> 1) & 3)) << 4);
  const char* gb1 = (const char*)(Bm + (size_t)(n0 + row1) * ldb) + ((sl ^ ((row1 >> 1) & 3)) << 4);
  u16* Abase = &As[0][0];
  u16* Bbase = &Bs[0][0];
  const int ldst0 = t * 8, ldst1 = 2048 + t * 8;

  int aoff[4], boff[4];
#pragma unroll
  for (int i = 0; i < 4; ++i) {
    int ra = wr * 64 + i * 16 + lq;
    aoff[i] = ra * 32 + ((lg ^ ((ra >> 1) & 3)) << 3);
    int rb = wc * 64 + i * 16 + lq;
    boff[i] = rb * 32 + ((lg ^ ((rb >> 1) & 3)) << 3);
  }

  f32x4 zero = {0.f, 0.f, 0.f, 0.f};
  f32x4 acc[4][4];
#pragma unroll
  for (int i = 0; i < 4; ++i)
#pragma unroll
    for (int j = 0; j < 4; ++j) acc[i][j] = zero;

  const int nk = K >> 5;
  gl_lds16(ga0, Abase + ldst0);
  gl_lds16(ga1, Abase + ldst1);
  gl_lds16(gb0, Bbase + ldst0);
  gl_lds16(gb1, Bbase + ldst1);
  __syncthreads();
  int cur = 0;
  for (int kt = 0; kt < nk; ++kt) {
    if (kt + 1 < nk) {
      const size_t ko = (size_t)(kt + 1) * 64;
      const int nb = (cur ^ 1) * 4096;
      gl_lds16(ga0 + ko, Abase + nb + ldst0);
      gl_lds16(ga1 + ko, Abase + nb + ldst1);
      gl_lds16(gb0 + ko, Bbase + nb + ldst0);
      gl_lds16(gb1 + ko, Bbase + nb + ldst1);
    }
    const int cb = cur * 4096;
    short8 af[4], bfr[4];
#pragma unroll
    for (int i = 0; i < 4; ++i) {
      af[i] = *(const short8*)(Abase + cb + aoff[i]);
      bfr[i] = *(const short8*)(Bbase + cb + boff[i]);
    }
#pragma unroll
    for (int i = 0; i < 4; ++i)
#pragma unroll
      for (int j = 0; j < 4; ++j)
        acc[i][j] = __builtin_amdgcn_mfma_f32_16x16x32_bf16(af[i], bfr[j], acc[i][j], 0, 0, 0);
    __syncthreads();
    cur ^= 1;
  }
#pragma unroll
  for (int i = 0; i < 4; ++i)
#pragma unroll
    for (int j = 0; j < 4; ++j) {
      const int row = m0 + wr * 64 + i * 16 + lg * 4;
      const int col = n0 + wc * 64 + j * 16 + lq;
      float* cp = C + (size_t)row * ldc + col;
#pragma unroll
      for (int r = 0; r < 4; ++r) cp[(size_t)r * ldc] = acc[i][j][r];
    }
}

// ---------------- per-token RMSNorm + RoPE + rank contraction -> Q,K,V (bf16) ------
__global__ __launch_bounds__(256)
void build_qkv(const float* __restrict__ P, const float* __restrict__ freqs,
               const float* __restrict__ qw, const float* __restrict__ kw,
               u16* __restrict__ Qg, u16* __restrict__ Kg, u16* __restrict__ Vg) {
  const int token = blockIdx.x;
  const int b = token >> 11, s = token & 2047;
  const int d = threadIdx.x;
  const float* row = P + (size_t)token * NPROJ;
  __shared__ float aL[128];
  __shared__ float rQ[6][256];
  __shared__ float rK[2][256];
  __shared__ float red[4][8];

  if (d < 128) aL[d] = row[d];
  float bq[6], bk[2], bv[2];
#pragma unroll
  for (int r = 0; r < 6; ++r) bq[r] = row[128 + r * 256 + d];
#pragma unroll
  for (int r = 0; r < 2; ++r) bk[r] = row[1664 + r * 256 + d];
#pragma unroll
  for (int r = 0; r < 2; ++r) bv[r] = row[2176 + r * 256 + d];

  float sq[8];
#pragma unroll
  for (int r = 0; r < 6; ++r) sq[r] = bq[r] * bq[r];
  sq[6] = bk[0] * bk[0];
  sq[7] = bk[1] * bk[1];
#pragma unroll
  for (int j = 0; j < 8; ++j) {
    sq[j] += __shfl_xor(sq[j], 32, 64);
    sq[j] += __shfl_xor(sq[j], 16, 64);
    sq[j] += __shfl_xor(sq[j], 8, 64);
    sq[j] += __shfl_xor(sq[j], 4, 64);
    sq[j] += __shfl_xor(sq[j], 2, 64);
    sq[j] += __shfl_xor(sq[j], 1, 64);
  }
  const int lane = d & 63, wv = d >> 6;
  if (lane == 0) {
#pragma unroll
    for (int j = 0; j < 8; ++j) red[wv][j] = sq[j];
  }
  __syncthreads();
  float inv[8];
#pragma unroll
  for (int j = 0; j < 8; ++j) {
    float ss = red[0][j] + red[1][j] + red[2][j] + red[3][j];
    inv[j] = rsqrtf(ss * (1.0f / 256.0f) + EPS_);
  }
  const float gq = 1.f + qw[d], gk = 1.f + kw[d];
#pragma unroll
  for (int r = 0; r < 6; ++r) rQ[r][d] = bq[r] * inv[r] * gq;
#pragma unroll
  for (int r = 0; r < 2; ++r) rK[r][d] = bk[r] * inv[6 + r] * gk;
  __syncthreads();

  const int dh = d & 127;
  const float co = freqs[(s * 128 + dh) * 2 + 0];
  const float sn = freqs[(s * 128 + dh) * 2 + 1];
  float q_ro[6], k_ro[2];
  if (d < 128) {
#pragma unroll
    for (int r = 0; r < 6; ++r) q_ro[r] = rQ[r][d] * co - rQ[r][d + 128] * sn;
#pragma unroll
    for (int r = 0; r < 2; ++r) k_ro[r] = rK[r][d] * co - rK[r][d + 128] * sn;
  } else {
#pragma unroll
    for (int r = 0; r < 6; ++r) q_ro[r] = rQ[r][d] * co + rQ[r][d - 128] * sn;
#pragma unroll
    for (int r = 0; r < 2; ++r) k_ro[r] = rK[r][d] * co + rK[r][d - 128] * sn;
  }
  const float qs = SCALE_ * (1.0f / 6.0f);
#pragma unroll
  for (int h = 0; h < 16; ++h) {
    float a = 0.f;
#pragma unroll
    for (int r = 0; r < 6; ++r) a += aL[h * 6 + r] * q_ro[r];
    Qg[((size_t)(b * H_ + h) * S_ + s) * D_ + d] = f2bf(a * qs);
  }
#pragma unroll
  for (int kv = 0; kv < 8; ++kv) {
    float ak = aL[96 + kv * 2] * k_ro[0] + aL[96 + kv * 2 + 1] * k_ro[1];
    Kg[((size_t)(b * KV_ + kv) * S_ + s) * D_ + d] = f2bf(ak * 0.5f);
    float av = aL[112 + kv * 2] * bv[0] + aL[112 + kv * 2 + 1] * bv[1];
    Vg[((size_t)(b * KV_ + kv) * S_ + s) * D_ + d] = f2bf(av * 0.5f);
  }
}

// ---------------- flash attention v3: 256 thr, 1 head, KVB=32, swapped QK^T -------
// 4 waves x 16 q-rows. K,V double-buffered; 1 barrier/tile; lane-local softmax rows.
__global__ __launch_bounds__(256, 2)
void attn_kernel(const u16* __restrict__ Qg, const u16* __restrict__ Kg,
                 const u16* __restrict__ VTg, u16* __restrict__ Og) {
  __shared__ __align__(16) u16 Kbuf[2][8192];   // 32 kv x 256 d, 16B-slot ^ (row&7)
  __shared__ __align__(16) u16 Vbuf[2][8192];   // 256 d x 32 kv, 16B-slot ^ ((d>>1)&3)
  __shared__ __align__(16) u16 Pbuf[4][512];    // per-wave 16q x 32kv, reader-linear layout

  const int t = threadIdx.x;
  const int lane = t & 63;
  const int lq = lane & 15, lg = lane >> 4;
  const int qw = t >> 6;                         // wave id = q16 block
  const int h = blockIdx.x, b = blockIdx.y;
  const int qt = 31 - blockIdx.z;                // LPT: heavy blocks dispatch first
  const int q0 = qt * 64;
  const int kvh = h >> 1;

  const u16* Kplane = Kg + (size_t)(b * KV_ + kvh) * S_ * D_;
  const u16* VTplane = VTg + (size_t)(b * KV_ + kvh) * D_ * S_;

  // Q fragment (B-operand): lane holds Q[q=lq][k=lg*8..+7] per 32-k slice
  const int qg = q0 + qw * 16 + lq;              // this lane's softmax q row
  const u16* Qrow = Qg + ((size_t)(b * H_ + h) * S_ + qg) * D_;
  short8 qf[8];
#pragma unroll
  for (int ks = 0; ks < 8; ++ks) qf[ks] = *(const short8*)(Qrow + ks * 32 + lg * 8);

  // staging source offsets (u16 units, 4 issues each)
  int ksrc[4], vsrc[4];
#pragma unroll
  for (int i = 0; i < 4; ++i) {
    const int kr = i * 8 + (t >> 5);
    ksrc[i] = kr * D_ + (((t & 31) ^ (kr & 7)) << 3);
    const int vr = i * 64 + (t >> 2);
    vsrc[i] = vr * S_ + (((t & 3) ^ ((vr >> 1) & 3)) << 3);
  }

  f32x4 zero = {0.f, 0.f, 0.f, 0.f};
  f32x4 oacc[16];
#pragma unroll
  for (int db = 0; db < 16; ++db) oacc[db] = zero;
  float m_s = NEG_, l_s = 0.f;                   // per-lane row stats (q = qg)

  const int qro = q0 + qw * 16 + lg * 4;         // oacc row base
  const int nt = 2 * (qt + 1);

#pragma unroll
  for (int i = 0; i < 4; ++i) {
    gl_lds16(Kplane + ksrc[i], &Kbuf[0][0] + (i * 256 + t) * 8);
    gl_lds16(VTplane + vsrc[i], &Vbuf[0][0] + (i * 256 + t) * 8);
  }
  __syncthreads();
  int cur = 0;
  for (int it = 0; it < nt; ++it) {
    const int kv0 = it * 32;
    // ---- prefetch next tile first (loads fly under the whole tile's compute)
    if (it + 1 < nt) {
      const u16* kp = Kplane + (size_t)(it + 1) * 32 * D_;
      const u16* vp = VTplane + (it + 1) * 32;
      u16* kd = &Kbuf[cur ^ 1][0];
      u16* vd = &Vbuf[cur ^ 1][0];
#pragma unroll
      for (int i = 0; i < 4; ++i) {
        gl_lds16(kp + ksrc[i], kd + (i * 256 + t) * 8);
        gl_lds16(vp + vsrc[i], vd + (i * 256 + t) * 8);
      }
    }
    // ---- QK^T swapped: sacc = K x Q^T -> rows kv, cols q
    const u16* Kb = &Kbuf[cur][0];
    f32x4 sacc[2];
    sacc[0] = zero; sacc[1] = zero;
    __builtin_amdgcn_s_setprio(1);
#pragma unroll
    for (int kb = 0; kb < 2; ++kb) {
      const int rbase = (kb * 16 + lq) * 256;
      const int sw = lq & 7;
#pragma unroll
      for (int ks = 0; ks < 8; ++ks) {
        short8 kf = *(const short8*)(Kb + rbase + (((ks * 4 + lg) ^ sw) << 3));
        sacc[kb] = __builtin_amdgcn_mfma_f32_16x16x32_bf16(kf, qf[ks], sacc[kb], 0, 0, 0);
      }
    }
    __builtin_amdgcn_s_setprio(0);
    // ---- softcap + causal mask; lane holds 8 scores of row q=qg, kv=kv0+16kb+4lg+r
    const bool tail = (it >= 2 * qt);
#pragma unroll
    for (int kb = 0; kb < 2; ++kb)
#pragma unroll
      for (int r = 0; r < 4; ++r) {
        float x = sacc[kb][r];
        const float e = __expf(-fabsf(x) * 0.04f);
        const float th = (1.f - e) * __builtin_amdgcn_rcpf(1.f + e);
        x = copysignf(50.0f * th, x);
        if (tail && (kv0 + kb * 16 + lg * 4 + r > qg)) x = NEG_;
        sacc[kb][r] = x;
      }
    // ---- row max: 7 in-lane + 2 shuffles
    float vmax = fmaxf(fmaxf(fmaxf(sacc[0][0], sacc[0][1]), fmaxf(sacc[0][2], sacc[0][3])),
                       fmaxf(fmaxf(sacc[1][0], sacc[1][1]), fmaxf(sacc[1][2], sacc[1][3])));
    vmax = fmaxf(vmax, __shfl_xor(vmax, 16, 64));
    vmax = fmaxf(vmax, __shfl_xor(vmax, 32, 64));
    // ---- T13 defer-max
    if (__any(vmax > m_s + 8.f)) {
      const float mn = fmaxf(m_s, vmax);
      const float c = __expf(m_s - mn);
      m_s = mn;
      l_s *= c;
      float c4[4];
#pragma unroll
      for (int r = 0; r < 4; ++r) c4[r] = __shfl(c, lg * 4 + r, 16);
#pragma unroll
      for (int db = 0; db < 16; ++db) {
        oacc[db][0] *= c4[0]; oacc[db][1] *= c4[1];
        oacc[db][2] *= c4[2]; oacc[db][3] *= c4[3];
      }
    }
    // ---- exp + row sum: in-lane + 2 shuffles
    float ps = 0.f;
#pragma unroll
    for (int kb = 0; kb < 2; ++kb)
#pragma unroll
      for (int r = 0; r < 4; ++r) {
        const float p = __expf(sacc[kb][r] - m_s);
        sacc[kb][r] = p;
        ps += p;
      }
    ps += __shfl_xor(ps, 16, 64);
    ps += __shfl_xor(ps, 32, 64);
    l_s += ps;
    // ---- P -> LDS: value (q=lq, kv) stored at byte 16q + 256*(kv>>3) + 2*(kv&7)
    u16* Pw = &Pbuf[qw][0];
#pragma unroll
    for (int kb = 0; kb < 2; ++kb) {
      ushort4 pk;
      pk.x = f2bf(sacc[kb][0]); pk.y = f2bf(sacc[kb][1]);
      pk.z = f2bf(sacc[kb][2]); pk.w = f2bf(sacc[kb][3]);
      *(ushort4*)(Pw + 8 * lq + 128 * (2 * kb + (lg >> 1)) + 4 * (lg & 1)) = pk;
    }
    // reader: lane wants P[q=lane&15][kv=(lane>>4)*8..+7] = contiguous 16B at lane*16
    short8 pf = *(const short8*)(Pw + lane * 8);
    // ---- PV from Vbuf[cur]
    const u16* Vb = &Vbuf[cur][0];
    __builtin_amdgcn_s_setprio(1);
#pragma unroll
    for (int db = 0; db < 16; ++db) {
      const int d = db * 16 + lq;
      short8 vf = *(const short8*)(Vb + d * 32 + ((lg ^ ((lq >> 1) & 3)) << 3));
      oacc[db] = __builtin_amdgcn_mfma_f32_16x16x32_bf16(pf, vf, oacc[db], 0, 0, 0);
    }
    __builtin_amdgcn_s_setprio(0);
    __syncthreads();   // all waves done with [cur]; prefetch into [cur^1] drained
    cur ^= 1;
  }
  // ---- epilogue: per-row 1/l via bpermute, write bf16
  const float invl = __builtin_amdgcn_rcpf(l_s);
  float inv4[4];
#pragma unroll
  for (int r = 0; r < 4; ++r) inv4[r] = __shfl(invl, lg * 4 + r, 16);
#pragma unroll
  for (int r = 0; r < 4; ++r) {
    u16* orow = Og + (size_t)(b * S_ + qro + r) * HD_ + h * D_;
#pragma unroll
    for (int db = 0; db < 16; ++db) orow[db * 16 + lq] = f2bf(oacc[db][r] * inv4[r]);
  }
}

// ---------------- launcher ----------------
extern "C" void kernel_launch(void* const* d_in, const int* in_sizes, int n_in,
                              void* d_out, int out_size, void* d_ws, size_t ws_size,
                              hipStream_t stream) {
  const float* hs    = (const float*)d_in[0];
  const float* freqs = (const float*)d_in[1];
  const float* W_A_q = (const float*)d_in[8];
  const float* W_A_k = (const float*)d_in[9];
  const float* W_A_v = (const float*)d_in[10];
  const float* W_B_q = (const float*)d_in[11];
  const float* W_B_k = (const float*)d_in[12];
  const float* W_B_v = (const float*)d_in[13];
  const float* Wo    = (const float*)d_in[14];
  const float* qw    = (const float*)d_in[15];
  const float* kw    = (const float*)d_in[16];
  float* out = (float*)d_out;

  char* ws = (char*)d_ws;
  u16* hsb = (u16*)(ws);                    // 4096x3584 bf16
  u16* WT  = (u16*)(ws + 29360128);         // 2688x3584 bf16
  u16* WoT = (u16*)(ws + 48627712);         // 3584x4096 bf16
  u16* Qg  = (u16*)(ws + 77987840);         // (B,H,S,D) bf16
  u16* Kg  = (u16*)(ws + 111542272);        // (B,KV,S,D) bf16
  u16* Vg  = (u16*)(ws + 128319488);        // (B,KV,S,D) bf16
  u16* VTg = (u16*)(ws + 145096704);        // (B,KV,D,S) bf16
  u16* AOg = (u16*)(ws + 161873920);        // (B*S, H*D) bf16
  float* Pout = (float*)d_out;              // 4096x2688 f32 scratch inside d_out

  cvt_f32_bf16<<<1024, 256, 0, stream>>>(hs, hsb, MTOK * HID_);
  transpose_f32_bf16<<<dim3(112, 3),   256, 0, stream>>>(W_A_q, WT + (size_t)0 * HID_,    HID_, 96);
  transpose_f32_bf16<<<dim3(112, 1),   256, 0, stream>>>(W_A_k, WT + (size_t)96 * HID_,   HID_, 16);
  transpose_f32_bf16<<<dim3(112, 1),   256, 0, stream>>>(W_A_v, WT + (size_t)112 * HID_,  HID_, 16);
  transpose_f32_bf16<<<dim3(112, 48),  256, 0, stream>>>(W_B_q, WT + (size_t)128 * HID_,  HID_, 1536);
  transpose_f32_bf16<<<dim3(112, 16),  256, 0, stream>>>(W_B_k, WT + (size_t)1664 * HID_, HID_, 512);
  transpose_f32_bf16<<<dim3(112, 16),  256, 0, stream>>>(W_B_v, WT + (size_t)2176 * HID_, HID_, 512);
  transpose_f32_bf16<<<dim3(128, 112), 256, 0, stream>>>(Wo, WoT, HD_, HID_);

  gemm_bt<<<dim3(32, 21), 256, 0, stream>>>(hsb, WT, Pout, MTOK, NPROJ, HID_, HID_, HID_, NPROJ);
  build_qkv<<<4096, 256, 0, stream>>>(Pout, freqs, qw, kw, Qg, Kg, Vg);
  transpose_bf16_b<<<dim3(64, 8, 16), 256, 0, stream>>>(Vg, VTg, S_, D_);
  attn_kernel<<<dim3(16, 2, 32), 256, 0, stream>>>(Qg, Kg, VTg, AOg);
  gemm_bt<<<dim3(32, 28), 256, 0, stream>>>(AOg, WoT, out, MTOK, HID_, HD_, HD_, HD_, HID_);
}

// Round 4
// 431.429 us; speedup vs baseline: 1.9015x; 1.0894x over previous
//
#include <hip/hip_runtime.h>

// ---------------- problem constants ----------------
#define B_    2
#define S_    2048
#define HID_  3584
#define H_    16
#define KV_   8
#define D_    256
#define RQ_   6
#define NPROJ 2688
#define HD_   4096
#define MTOK  4096
#define EPS_  1e-6f
#define NEG_  -2.3819763e38f
#define SCALE_ 0.0625f   // 256^-0.5

typedef unsigned short u16;
typedef __attribute__((ext_vector_type(8))) short short8;
typedef __attribute__((ext_vector_type(4))) float f32x4;

__device__ __forceinline__ u16 f2bf(float f) {
  unsigned u = __float_as_uint(f);
  u += 0x7fffu + ((u >> 16) & 1u);
  return (u16)(u >> 16);
}

__device__ __forceinline__ void gl_lds16(const void* g, void* l) {
  __builtin_amdgcn_global_load_lds((__attribute__((address_space(1))) void*)g,
                                   (__attribute__((address_space(3))) void*)l, 16, 0, 0);
}

// ---------------- elementwise f32 -> bf16 ----------------
__global__ __launch_bounds__(256) void cvt_f32_bf16(const float* __restrict__ src,
                                                    u16* __restrict__ dst, int n) {
  int i = blockIdx.x * 256 + threadIdx.x;
  const int stride = gridDim.x * 256;
  const int n4 = n >> 2;
  for (; i < n4; i += stride) {
    float4 v = ((const float4*)src)[i];
    ushort4 o;
    o.x = f2bf(v.x); o.y = f2bf(v.y); o.z = f2bf(v.z); o.w = f2bf(v.w);
    ((ushort4*)dst)[i] = o;
  }
}

// ---------------- tiled transpose f32(RxC) -> bf16(CxR) ----------------
__global__ __launch_bounds__(256) void transpose_f32_bf16(const float* __restrict__ src,
                                                          u16* __restrict__ dst, int R, int C) {
  __shared__ float tile[32][33];
  const int tx = threadIdx.x & 31, ty = threadIdx.x >> 5;
  const int r0 = blockIdx.x << 5, c0 = blockIdx.y << 5;
#pragma unroll
  for (int j = 0; j < 4; ++j) {
    int r = r0 + ty + j * 8, c = c0 + tx;
    tile[ty + j * 8][tx] = (r < R && c < C) ? src[(size_t)r * C + c] : 0.f;
  }
  __syncthreads();
#pragma unroll
  for (int j = 0; j < 4; ++j) {
    int cc = c0 + ty + j * 8, rr = r0 + tx;
    if (cc < C && rr < R) dst[(size_t)cc * R + rr] = f2bf(tile[tx][ty + j * 8]);
  }
}

// ---------------- tiled transpose bf16(RxC)->bf16(CxR), batched z ----------------
__global__ __launch_bounds__(256) void transpose_bf16_b(const u16* __restrict__ src,
                                                        u16* __restrict__ dst, int R, int C) {
  __shared__ u16 tile[32][34];
  const size_t plane = (size_t)R * C;
  const u16* s = src + (size_t)blockIdx.z * plane;
  u16* d = dst + (size_t)blockIdx.z * plane;
  const int tx = threadIdx.x & 31, ty = threadIdx.x >> 5;
  const int r0 = blockIdx.x << 5, c0 = blockIdx.y << 5;
#pragma unroll
  for (int j = 0; j < 4; ++j) {
    int r = r0 + ty + j * 8, c = c0 + tx;
    tile[ty + j * 8][tx] = (r < R && c < C) ? s[(size_t)r * C + c] : (u16)0;
  }
  __syncthreads();
#pragma unroll
  for (int j = 0; j < 4; ++j) {
    int cc = c0 + ty + j * 8, rr = r0 + tx;
    if (cc < C && rr < R) d[(size_t)cc * R + rr] = tile[tx][ty + j * 8];
  }
}

// ---------------- 256x256 8-phase GEMM (T2+T3+T4+T5), A(MxK) rm, Bm(NxK) rm -------
// 512 thr = 8 waves (2M x 4N), BK=64, LDS 128 KiB double-buffered.
// LDS: [buf][mat A/B][half 128-rows][16 subtiles of 16x32 elems, 1024 B each, st_16x32
// swizzle: byte bit5 ^= bit9]. Staged via pre-swizzled global src + linear gl_lds dest.
// Counted vmcnt: regions {A-sk0,B-sk0,A-sk1,B-sk1} staged 1/phase; vmcnt(4) at phases
// 0,2 keeps 4 loads in flight across barriers; vmcnt(0) only on the last tile.
__global__ __launch_bounds__(512, 2)
void gemm256(const u16* __restrict__ A, const u16* __restrict__ Bm, float* __restrict__ C,
             int N, int lda, int ldb, int ldc, int NT) {
  __shared__ __align__(16) u16 lds[2][2][2][8192];
  const int t = threadIdx.x;
  const int lane = t & 63;
  const int lq = lane & 15, lg = lane >> 4;
  const int w = t >> 6;
  const int wm = w >> 2, wn = w & 3;
  const int bm0 = blockIdx.x * 256, bn0 = blockIdx.y * 256;

  // staging: wave w stages subtile-row w of each half; lane l covers (r'=l>>2,
  // k' = (l&3)*8 ^ ((l>>5)<<4)) -- the inverse (== forward) st_16x32 swizzle.
  const int rsub = lane >> 2;
  const int ksub = ((lane & 3) << 3) ^ ((lane >> 5) << 4);
  const u16* pa0 = A + (size_t)(bm0 + w * 16 + rsub) * lda + ksub;
  const u16* pa1 = pa0 + (size_t)128 * lda;
  const u16* pb0 = Bm + (size_t)(bn0 + w * 16 + rsub) * ldb + ksub;
  const u16* pb1 = pb0 + (size_t)128 * ldb;

  // frag ds_read offset within a half-region (u16 units), swizzled
  const int rdo = lq * 32 + ((lg << 3) ^ (((lq >> 3) & 1) << 4));
  const int bsub = (wn & 1) << 3;   // B subtile index base: bsub + 2n + ks

  f32x4 zero = {0.f, 0.f, 0.f, 0.f};
  f32x4 acc[8][4];
#pragma unroll
  for (int m = 0; m < 8; ++m)
#pragma unroll
    for (int n = 0; n < 4; ++n) acc[m][n] = zero;

  // prologue: stage tile 0 into buf0, region order A-sk0, B-sk0, A-sk1, B-sk1
  gl_lds16(pa0,      &lds[0][0][0][(w * 2 + 0) * 512]);
  gl_lds16(pa1,      &lds[0][0][1][(w * 2 + 0) * 512]);
  gl_lds16(pb0,      &lds[0][1][0][(w * 2 + 0) * 512]);
  gl_lds16(pb1,      &lds[0][1][1][(w * 2 + 0) * 512]);
  gl_lds16(pa0 + 32, &lds[0][0][0][(w * 2 + 1) * 512]);
  gl_lds16(pa1 + 32, &lds[0][0][1][(w * 2 + 1) * 512]);
  gl_lds16(pb0 + 32, &lds[0][1][0][(w * 2 + 1) * 512]);
  gl_lds16(pb1 + 32, &lds[0][1][1][(w * 2 + 1) * 512]);

  int cur = 0;
  for (int T = 0; T < NT; ++T) {
    const bool pre = (T + 1) < NT;
    const size_t ko = (size_t)(T + 1) * 64;
    const u16* ab = &lds[cur][0][wm][0];
    const u16* bb = &lds[cur][1][wn >> 1][0];
    const int nb = cur ^ 1;

    // ======== phase 0: ks=0, m0-3 ========
    asm volatile("s_waitcnt vmcnt(4)" ::: "memory");
    __builtin_amdgcn_s_barrier();
    __builtin_amdgcn_sched_barrier(0);
    short8 af[4], bf[4];
#pragma unroll
    for (int m = 0; m < 4; ++m) af[m] = *(const short8*)(ab + (m * 2 + 0) * 512 + rdo);
#pragma unroll
    for (int n = 0; n < 4; ++n) bf[n] = *(const short8*)(bb + (bsub + n * 2 + 0) * 512 + rdo);
    if (pre) {
      gl_lds16(pa0 + ko, &lds[nb][0][0][(w * 2 + 0) * 512]);
      gl_lds16(pa1 + ko, &lds[nb][0][1][(w * 2 + 0) * 512]);
    }
    __builtin_amdgcn_s_setprio(1);
#pragma unroll
    for (int m = 0; m < 4; ++m)
#pragma unroll
      for (int n = 0; n < 4; ++n)
        acc[m][n] = __builtin_amdgcn_mfma_f32_16x16x32_bf16(af[m], bf[n], acc[m][n], 0, 0, 0);
    __builtin_amdgcn_s_setprio(0);

    // ======== phase 1: ks=0, m4-7 (reuse bf) ========
    short8 ag[4];
#pragma unroll
    for (int m = 0; m < 4; ++m) ag[m] = *(const short8*)(ab + ((m + 4) * 2 + 0) * 512 + rdo);
    if (pre) {
      gl_lds16(pb0 + ko, &lds[nb][1][0][(w * 2 + 0) * 512]);
      gl_lds16(pb1 + ko, &lds[nb][1][1][(w * 2 + 0) * 512]);
    }
    __builtin_amdgcn_s_setprio(1);
#pragma unroll
    for (int m = 0; m < 4; ++m)
#pragma unroll
      for (int n = 0; n < 4; ++n)
        acc[m + 4][n] = __builtin_amdgcn_mfma_f32_16x16x32_bf16(ag[m], bf[n], acc[m + 4][n], 0, 0, 0);
    __builtin_amdgcn_s_setprio(0);

    // ======== phase 2: ks=1, m0-3 ========
    if (pre) { asm volatile("s_waitcnt vmcnt(4)" ::: "memory"); }
    else     { asm volatile("s_waitcnt vmcnt(0)" ::: "memory"); }
    __builtin_amdgcn_s_barrier();
    __builtin_amdgcn_sched_barrier(0);
    short8 af2[4], bf2[4];
#pragma unroll
    for (int m = 0; m < 4; ++m) af2[m] = *(const short8*)(ab + (m * 2 + 1) * 512 + rdo);
#pragma unroll
    for (int n = 0; n < 4; ++n) bf2[n] = *(const short8*)(bb + (bsub + n * 2 + 1) * 512 + rdo);
    if (pre) {
      gl_lds16(pa0 + ko + 32, &lds[nb][0][0][(w * 2 + 1) * 512]);
      gl_lds16(pa1 + ko + 32, &lds[nb][0][1][(w * 2 + 1) * 512]);
    }
    __builtin_amdgcn_s_setprio(1);
#pragma unroll
    for (int m = 0; m < 4; ++m)
#pragma unroll
      for (int n = 0; n < 4; ++n)
        acc[m][n] = __builtin_amdgcn_mfma_f32_16x16x32_bf16(af2[m], bf2[n], acc[m][n], 0, 0, 0);
    __builtin_amdgcn_s_setprio(0);

    // ======== phase 3: ks=1, m4-7 (reuse bf2) ========
    short8 ag2[4];
#pragma unroll
    for (int m = 0; m < 4; ++m) ag2[m] = *(const short8*)(ab + ((m + 4) * 2 + 1) * 512 + rdo);
    if (pre) {
      gl_lds16(pb0 + ko + 32, &lds[nb][1][0][(w * 2 + 1) * 512]);
      gl_lds16(pb1 + ko + 32, &lds[nb][1][1][(w * 2 + 1) * 512]);
    }
    __builtin_amdgcn_s_setprio(1);
#pragma unroll
    for (int m = 0; m < 4; ++m)
#pragma unroll
      for (int n = 0; n < 4; ++n)
        acc[m + 4][n] = __builtin_amdgcn_mfma_f32_16x16x32_bf16(ag2[m], bf2[n], acc[m + 4][n], 0, 0, 0);
    __builtin_amdgcn_s_setprio(0);

    cur ^= 1;
  }

  // ---- epilogue (cols guarded for N not multiple of 256)
#pragma unroll
  for (int m = 0; m < 8; ++m) {
    const int row = bm0 + wm * 128 + m * 16 + lg * 4;
#pragma unroll
    for (int n = 0; n < 4; ++n) {
      const int col = bn0 + wn * 64 + n * 16 + lq;
      if (col < N) {
        float* cp = C + (size_t)row * ldc + col;
        cp[0] = acc[m][n][0];
        cp[(size_t)ldc] = acc[m][n][1];
        cp[(size_t)2 * ldc] = acc[m][n][2];
        cp[(size_t)3 * ldc] = acc[m][n][3];
      }
    }
  }
}

// ---------------- per-token RMSNorm + RoPE + rank contraction -> Q,K,V (bf16) ------
__global__ __launch_bounds__(256)
void build_qkv(const float* __restrict__ P, const float* __restrict__ freqs,
               const float* __restrict__ qw, const float* __restrict__ kw,
               u16* __restrict__ Qg, u16* __restrict__ Kg, u16* __restrict__ Vg) {
  const int token = blockIdx.x;
  const int b = token >> 11, s = token & 2047;
  const int d = threadIdx.x;
  const float* row = P + (size_t)token * NPROJ;
  __shared__ float aL[128];
  __shared__ float rQ[6][256];
  __shared__ float rK[2][256];
  __shared__ float red[4][8];

  if (d < 128) aL[d] = row[d];
  float bq[6], bk[2], bv[2];
#pragma unroll
  for (int r = 0; r < 6; ++r) bq[r] = row[128 + r * 256 + d];
#pragma unroll
  for (int r = 0; r < 2; ++r) bk[r] = row[1664 + r * 256 + d];
#pragma unroll
  for (int r = 0; r < 2; ++r) bv[r] = row[2176 + r * 256 + d];

  float sq[8];
#pragma unroll
  for (int r = 0; r < 6; ++r) sq[r] = bq[r] * bq[r];
  sq[6] = bk[0] * bk[0];
  sq[7] = bk[1] * bk[1];
#pragma unroll
  for (int j = 0; j < 8; ++j) {
    sq[j] += __shfl_xor(sq[j], 32, 64);
    sq[j] += __shfl_xor(sq[j], 16, 64);
    sq[j] += __shfl_xor(sq[j], 8, 64);
    sq[j] += __shfl_xor(sq[j], 4, 64);
    sq[j] += __shfl_xor(sq[j], 2, 64);
    sq[j] += __shfl_xor(sq[j], 1, 64);
  }
  const int lane = d & 63, wv = d >> 6;
  if (lane == 0) {
#pragma unroll
    for (int j = 0; j < 8; ++j) red[wv][j] = sq[j];
  }
  __syncthreads();
  float inv[8];
#pragma unroll
  for (int j = 0; j < 8; ++j) {
    float ss = red[0][j] + red[1][j] + red[2][j] + red[3][j];
    inv[j] = rsqrtf(ss * (1.0f / 256.0f) + EPS_);
  }
  const float gq = 1.f + qw[d], gk = 1.f + kw[d];
#pragma unroll
  for (int r = 0; r < 6; ++r) rQ[r][d] = bq[r] * inv[r] * gq;
#pragma unroll
  for (int r = 0; r < 2; ++r) rK[r][d] = bk[r] * inv[6 + r] * gk;
  __syncthreads();

  const int dh = d & 127;
  const float co = freqs[(s * 128 + dh) * 2 + 0];
  const float sn = freqs[(s * 128 + dh) * 2 + 1];
  float q_ro[6], k_ro[2];
  if (d < 128) {
#pragma unroll
    for (int r = 0; r < 6; ++r) q_ro[r] = rQ[r][d] * co - rQ[r][d + 128] * sn;
#pragma unroll
    for (int r = 0; r < 2; ++r) k_ro[r] = rK[r][d] * co - rK[r][d + 128] * sn;
  } else {
#pragma unroll
    for (int r = 0; r < 6; ++r) q_ro[r] = rQ[r][d] * co + rQ[r][d - 128] * sn;
#pragma unroll
    for (int r = 0; r < 2; ++r) k_ro[r] = rK[r][d] * co + rK[r][d - 128] * sn;
  }
  const float qs = SCALE_ * (1.0f / 6.0f);
#pragma unroll
  for (int h = 0; h < 16; ++h) {
    float a = 0.f;
#pragma unroll
    for (int r = 0; r < 6; ++r) a += aL[h * 6 + r] * q_ro[r];
    Qg[((size_t)(b * H_ + h) * S_ + s) * D_ + d] = f2bf(a * qs);
  }
#pragma unroll
  for (int kv = 0; kv < 8; ++kv) {
    float ak = aL[96 + kv * 2] * k_ro[0] + aL[96 + kv * 2 + 1] * k_ro[1];
    Kg[((size_t)(b * KV_ + kv) * S_ + s) * D_ + d] = f2bf(ak * 0.5f);
    float av = aL[112 + kv * 2] * bv[0] + aL[112 + kv * 2 + 1] * bv[1];
    Vg[((size_t)(b * KV_ + kv) * S_ + s) * D_ + d] = f2bf(av * 0.5f);
  }
}

// ---------------- flash attention v3: 256 thr, 1 head, KVB=32, swapped QK^T -------
__global__ __launch_bounds__(256, 2)
void attn_kernel(const u16* __restrict__ Qg, const u16* __restrict__ Kg,
                 const u16* __restrict__ VTg, u16* __restrict__ Og) {
  __shared__ __align__(16) u16 Kbuf[2][8192];
  __shared__ __align__(16) u16 Vbuf[2][8192];
  __shared__ __align__(16) u16 Pbuf[4][512];

  const int t = threadIdx.x;
  const int lane = t & 63;
  const int lq = lane & 15, lg = lane >> 4;
  const int qw = t >> 6;
  const int h = blockIdx.x, b = blockIdx.y;
  const int qt = 31 - blockIdx.z;
  const int q0 = qt * 64;
  const int kvh = h >> 1;

  const u16* Kplane = Kg + (size_t)(b * KV_ + kvh) * S_ * D_;
  const u16* VTplane = VTg + (size_t)(b * KV_ + kvh) * D_ * S_;

  const int qg = q0 + qw * 16 + lq;
  const u16* Qrow = Qg + ((size_t)(b * H_ + h) * S_ + qg) * D_;
  short8 qf[8];
#pragma unroll
  for (int ks = 0; ks < 8; ++ks) qf[ks] = *(const short8*)(Qrow + ks * 32 + lg * 8);

  int ksrc[4], vsrc[4];
#pragma unroll
  for (int i = 0; i < 4; ++i) {
    const int kr = i * 8 + (t >> 5);
    ksrc[i] = kr * D_ + (((t & 31) ^ (kr & 7)) << 3);
    const int vr = i * 64 + (t >> 2);
    vsrc[i] = vr * S_ + (((t & 3) ^ ((vr >> 1) & 3)) << 3);
  }

  f32x4 zero = {0.f, 0.f, 0.f, 0.f};
  f32x4 oacc[16];
#pragma unroll
  for (int db = 0; db < 16; ++db) oacc[db] = zero;
  float m_s = NEG_, l_s = 0.f;

  const int qro = q0 + qw * 16 + lg * 4;
  const int nt = 2 * (qt + 1);

#pragma unroll
  for (int i = 0; i < 4; ++i) {
    gl_lds16(Kplane + ksrc[i], &Kbuf[0][0] + (i * 256 + t) * 8);
    gl_lds16(VTplane + vsrc[i], &Vbuf[0][0] + (i * 256 + t) * 8);
  }
  __syncthreads();
  int cur = 0;
  for (int it = 0; it < nt; ++it) {
    const int kv0 = it * 32;
    if (it + 1 < nt) {
      const u16* kp = Kplane + (size_t)(it + 1) * 32 * D_;
      const u16* vp = VTplane + (it + 1) * 32;
      u16* kd = &Kbuf[cur ^ 1][0];
      u16* vd = &Vbuf[cur ^ 1][0];
#pragma unroll
      for (int i = 0; i < 4; ++i) {
        gl_lds16(kp + ksrc[i], kd + (i * 256 + t) * 8);
        gl_lds16(vp + vsrc[i], vd + (i * 256 + t) * 8);
      }
    }
    const u16* Kb = &Kbuf[cur][0];
    f32x4 sacc[2];
    sacc[0] = zero; sacc[1] = zero;
    __builtin_amdgcn_s_setprio(1);
#pragma unroll
    for (int kb = 0; kb < 2; ++kb) {
      const int rbase = (kb * 16 + lq) * 256;
      const int sw = lq & 7;
#pragma unroll
      for (int ks = 0; ks < 8; ++ks) {
        short8 kf = *(const short8*)(Kb + rbase + (((ks * 4 + lg) ^ sw) << 3));
        sacc[kb] = __builtin_amdgcn_mfma_f32_16x16x32_bf16(kf, qf[ks], sacc[kb], 0, 0, 0);
      }
    }
    __builtin_amdgcn_s_setprio(0);
    const bool tail = (it >= 2 * qt);
#pragma unroll
    for (int kb = 0; kb < 2; ++kb)
#pragma unroll
      for (int r = 0; r < 4; ++r) {
        float x = sacc[kb][r];
        const float e = __expf(-fabsf(x) * 0.04f);
        const float th = (1.f - e) * __builtin_amdgcn_rcpf(1.f + e);
        x = copysignf(50.0f * th, x);
        if (tail && (kv0 + kb * 16 + lg * 4 + r > qg)) x = NEG_;
        sacc[kb][r] = x;
      }
    float vmax = fmaxf(fmaxf(fmaxf(sacc[0][0], sacc[0][1]), fmaxf(sacc[0][2], sacc[0][3])),
                       fmaxf(fmaxf(sacc[1][0], sacc[1][1]), fmaxf(sacc[1][2], sacc[1][3])));
    vmax = fmaxf(vmax, __shfl_xor(vmax, 16, 64));
    vmax = fmaxf(vmax, __shfl_xor(vmax, 32, 64));
    if (__any(vmax > m_s + 8.f)) {
      const float mn = fmaxf(m_s, vmax);
      const float c = __expf(m_s - mn);
      m_s = mn;
      l_s *= c;
      float c4[4];
#pragma unroll
      for (int r = 0; r < 4; ++r) c4[r] = __shfl(c, lg * 4 + r, 16);
#pragma unroll
      for (int db = 0; db < 16; ++db) {
        oacc[db][0] *= c4[0]; oacc[db][1] *= c4[1];
        oacc[db][2] *= c4[2]; oacc[db][3] *= c4[3];
      }
    }
    float ps = 0.f;
#pragma unroll
    for (int kb = 0; kb < 2; ++kb)
#pragma unroll
      for (int r = 0; r < 4; ++r) {
        const float p = __expf(sacc[kb][r] - m_s);
        sacc[kb][r] = p;
        ps += p;
      }
    ps += __shfl_xor(ps, 16, 64);
    ps += __shfl_xor(ps, 32, 64);
    l_s += ps;
    u16* Pw = &Pbuf[qw][0];
#pragma unroll
    for (int kb = 0; kb < 2; ++kb) {
      ushort4 pk;
      pk.x = f2bf(sacc[kb][0]); pk.y = f2bf(sacc[kb][1]);
      pk.z = f2bf(sacc[kb][2]); pk.w = f2bf(sacc[kb][3]);
      *(ushort4*)(Pw + 8 * lq + 128 * (2 * kb + (lg >> 1)) + 4 * (lg & 1)) = pk;
    }
    short8 pf = *(const short8*)(Pw + lane * 8);
    const u16* Vb = &Vbuf[cur][0];
    __builtin_amdgcn_s_setprio(1);
#pragma unroll
    for (int db = 0; db < 16; ++db) {
      const int d = db * 16 + lq;
      short8 vf = *(const short8*)(Vb + d * 32 + ((lg ^ ((lq >> 1) & 3)) << 3));
      oacc[db] = __builtin_amdgcn_mfma_f32_16x16x32_bf16(pf, vf, oacc[db], 0, 0, 0);
    }
    __builtin_amdgcn_s_setprio(0);
    __syncthreads();
    cur ^= 1;
  }
  const float invl = __builtin_amdgcn_rcpf(l_s);
  float inv4[4];
#pragma unroll
  for (int r = 0; r < 4; ++r) inv4[r] = __shfl(invl, lg * 4 + r, 16);
#pragma unroll
  for (int r = 0; r < 4; ++r) {
    u16* orow = Og + (size_t)(b * S_ + qro + r) * HD_ + h * D_;
#pragma unroll
    for (int db = 0; db < 16; ++db) orow[db * 16 + lq] = f2bf(oacc[db][r] * inv4[r]);
  }
}

// ---------------- launcher ----------------
extern "C" void kernel_launch(void* const* d_in, const int* in_sizes, int n_in,
                              void* d_out, int out_size, void* d_ws, size_t ws_size,
                              hipStream_t stream) {
  const float* hs    = (const float*)d_in[0];
  const float* freqs = (const float*)d_in[1];
  const float* W_A_q = (const float*)d_in[8];
  const float* W_A_k = (const float*)d_in[9];
  const float* W_A_v = (const float*)d_in[10];
  const float* W_B_q = (const float*)d_in[11];
  const float* W_B_k = (const float*)d_in[12];
  const float* W_B_v = (const float*)d_in[13];
  const float* Wo    = (const float*)d_in[14];
  const float* qw    = (const float*)d_in[15];
  const float* kw    = (const float*)d_in[16];
  float* out = (float*)d_out;

  char* ws = (char*)d_ws;
  u16* hsb = (u16*)(ws);                    // 4096x3584 bf16
  u16* WT  = (u16*)(ws + 29360128);         // 2688x3584 bf16
  u16* WoT = (u16*)(ws + 48627712);         // 3584x4096 bf16
  u16* Qg  = (u16*)(ws + 77987840);         // (B,H,S,D) bf16
  u16* Kg  = (u16*)(ws + 111542272);        // (B,KV,S,D) bf16
  u16* Vg  = (u16*)(ws + 128319488);        // (B,KV,S,D) bf16
  u16* VTg = (u16*)(ws + 145096704);        // (B,KV,D,S) bf16
  u16* AOg = (u16*)(ws + 161873920);        // (B*S, H*D) bf16
  float* Pout = (float*)d_out;              // 4096x2688 f32 scratch inside d_out

  cvt_f32_bf16<<<1024, 256, 0, stream>>>(hs, hsb, MTOK * HID_);
  transpose_f32_bf16<<<dim3(112, 3),   256, 0, stream>>>(W_A_q, WT + (size_t)0 * HID_,    HID_, 96);
  transpose_f32_bf16<<<dim3(112, 1),   256, 0, stream>>>(W_A_k, WT + (size_t)96 * HID_,   HID_, 16);
  transpose_f32_bf16<<<dim3(112, 1),   256, 0, stream>>>(W_A_v, WT + (size_t)112 * HID_,  HID_, 16);
  transpose_f32_bf16<<<dim3(112, 48),  256, 0, stream>>>(W_B_q, WT + (size_t)128 * HID_,  HID_, 1536);
  transpose_f32_bf16<<<dim3(112, 16),  256, 0, stream>>>(W_B_k, WT + (size_t)1664 * HID_, HID_, 512);
  transpose_f32_bf16<<<dim3(112, 16),  256, 0, stream>>>(W_B_v, WT + (size_t)2176 * HID_, HID_, 512);
  transpose_f32_bf16<<<dim3(128, 112), 256, 0, stream>>>(Wo, WoT, HD_, HID_);

  gemm256<<<dim3(16, 11), 512, 0, stream>>>(hsb, WT, Pout, NPROJ, HID_, HID_, NPROJ, 56);
  build_qkv<<<4096, 256, 0, stream>>>(Pout, freqs, qw, kw, Qg, Kg, Vg);
  transpose_bf16_b<<<dim3(64, 8, 16), 256, 0, stream>>>(Vg, VTg, S_, D_);
  attn_kernel<<<dim3(16, 2, 32), 256, 0, stream>>>(Qg, Kg, VTg, AOg);
  gemm256<<<dim3(16, 14), 512, 0, stream>>>(AOg, WoT, out, HID_, HD_, HD_, HID_, 64);
}